// Round 14
// baseline (313.429 us; speedup 1.0000x reference)
//
#include <hip/hip_runtime.h>
#include <math.h>

#define F_IN   128
#define HIDC   32
#define NHEAD  4
#define CDIM   40
#define NEG_SLOPE 0.2f
#define BCAP   4096
#define OVCAP  16384
#define SCHUNK 4096

typedef __attribute__((ext_vector_type(8))) short bf16x8;   // 8 bf16 = 4 VGPRs
typedef __attribute__((ext_vector_type(4))) float f32x4;    // MFMA C/D

__device__ __forceinline__ float leakyf(float x) { return x > 0.f ? x : NEG_SLOPE * x; }

__device__ __forceinline__ float wred_sum(float v) {
#pragma unroll
    for (int o = 32; o > 0; o >>= 1) v += __shfl_xor(v, o, 64);
    return v;
}
__device__ __forceinline__ float sel4(float4 v, int h) {
    return (h == 0) ? v.x : (h == 1) ? v.y : (h == 2) ? v.z : v.w;
}
__device__ __forceinline__ unsigned pack2_bf16(float a, float b) {
    unsigned ua = __float_as_uint(a);
    unsigned ub = __float_as_uint(b);
    ua = (ua + 0x7FFFu + ((ua >> 16) & 1u)) >> 16;
    ub = (ub + 0x7FFFu + ((ub >> 16) & 1u)) >> 16;
    return ua | (ub << 16);
}
__device__ __forceinline__ float2 unpack2_bf16(unsigned p) {
    return make_float2(__uint_as_float(p << 16), __uint_as_float(p & 0xFFFF0000u));
}
__device__ __forceinline__ float bf2f(unsigned short u) {
    return __uint_as_float(((unsigned)u) << 16);
}

// ---- W pre-pack into MFMA B-fragment order --------------------------------
__global__ void wb_prep_kernel(const float* __restrict__ Wg, const float* __restrict__ Wc,
                               uint4* __restrict__ wbf)
{
    int b = blockIdx.x;            // nt*4 + ks, 0..39
    int lane = threadIdx.x;        // 0..63
    int nt = b >> 2, ks = b & 3;
    int c = nt * 16 + (lane & 15);
    int k0 = ks * 32 + (lane >> 4) * 8;
    unsigned u[4];
#pragma unroll
    for (int jj = 0; jj < 4; ++jj) {
        int k = k0 + 2 * jj;
        float a0 = (c < 128) ? Wg[(size_t)k * 128 + c] : Wc[(size_t)k * 32 + (c - 128)];
        float a1 = (c < 128) ? Wg[(size_t)(k + 1) * 128 + c] : Wc[(size_t)(k + 1) * 32 + (c - 128)];
        u[jj] = pack2_bf16(a0, a1);
    }
    wbf[(size_t)b * 64 + lane] = make_uint4(u[0], u[1], u[2], u[3]);
}

// ---- first-layer GEMM on MFMA; emits combined h1g[n,80u] + logits1 --------
__global__ __launch_bounds__(256) void gemm1_mfma_kernel(
    const float* __restrict__ X, const uint4* __restrict__ wbf,
    const float* __restrict__ aw_s, const float* __restrict__ aw_d,
    unsigned* __restrict__ h1g,
    float* __restrict__ as1, float* __restrict__ ad1, int n)
{
    __shared__ float Ct[64][164];
    __shared__ float sw[128], dw[128];
    const int tid = threadIdx.x;
    const int w = tid >> 6, lane = tid & 63;
    const int m = lane & 15, q = lane >> 4;
    const int node0 = blockIdx.x * 64;
    if (tid < 128) { sw[tid] = aw_s[tid]; dw[tid] = aw_d[tid]; }

    f32x4 acc[10];
#pragma unroll
    for (int t = 0; t < 10; ++t) acc[t] = (f32x4){0.f, 0.f, 0.f, 0.f};

    const int row = node0 + w * 16 + m;
    const bool rv = row < n;
#pragma unroll
    for (int ks = 0; ks < 4; ++ks) {
        uint4 pa = make_uint4(0u, 0u, 0u, 0u);
        if (rv) {
            const float* xr = X + (size_t)row * 128 + ks * 32 + q * 8;
            float4 a0 = *(const float4*)xr;
            float4 a1 = *(const float4*)(xr + 4);
            pa = make_uint4(pack2_bf16(a0.x, a0.y), pack2_bf16(a0.z, a0.w),
                            pack2_bf16(a1.x, a1.y), pack2_bf16(a1.z, a1.w));
        }
        bf16x8 af = *(bf16x8*)&pa;
#pragma unroll
        for (int nt = 0; nt < 10; ++nt) {
            uint4 pb = wbf[(size_t)(nt * 4 + ks) * 64 + lane];
            bf16x8 bfv = *(bf16x8*)&pb;
            acc[nt] = __builtin_amdgcn_mfma_f32_16x16x32_bf16(af, bfv, acc[nt], 0, 0, 0);
        }
    }
#pragma unroll
    for (int nt = 0; nt < 10; ++nt)
#pragma unroll
        for (int r = 0; r < 4; ++r)
            Ct[w * 16 + q * 4 + r][nt * 16 + m] = acc[nt][r];
    __syncthreads();

    // combined row: uints 0..63 = gat h1 (cols 0..127), 64..79 = gcn g1 (cols 128..159)
    for (int i = tid; i < 64 * 80; i += 256) {
        int nd = i / 80, u = i - nd * 80;
        int gn = node0 + nd;
        if (gn < n)
            h1g[(size_t)gn * 80 + u] = pack2_bf16(Ct[nd][2 * u], Ct[nd][2 * u + 1]);
    }
    {
        int nd = tid >> 2, h = tid & 3;
        int gn = node0 + nd;
        if (gn < n) {
            float s = 0.f, d = 0.f;
#pragma unroll
            for (int k = 0; k < HIDC; ++k) {
                float v = Ct[nd][h * HIDC + k];
                s = fmaf(v, sw[h * HIDC + k], s);
                d = fmaf(v, dw[h * HIDC + k], d);
            }
            as1[(size_t)gn * 4 + h] = s;
            ad1[(size_t)gn * 4 + h] = d;
        }
    }
}

// ---------------- CSR build: bucketed counting sort by dst ------------------
__global__ __launch_bounds__(256) void bucket_scatter_kernel(
    const int* __restrict__ src, const int* __restrict__ dst,
    unsigned* __restrict__ bcnt, unsigned* __restrict__ bpair,
    unsigned* __restrict__ ovf_cnt, uint2* __restrict__ ovf, int e, int nbuck)
{
    __shared__ unsigned hist[512];
    __shared__ unsigned base[512];
    const int t = threadIdx.x;
    const int lo = blockIdx.x * SCHUNK;
    const int hi = min(lo + SCHUNK, e);
    for (int i = t; i < nbuck; i += 256) hist[i] = 0;
    __syncthreads();
    for (int i = lo + t; i < hi; i += 256)
        atomicAdd(&hist[((unsigned)dst[i]) >> 7], 1u);
    __syncthreads();
    for (int i = t; i < nbuck; i += 256) {
        unsigned c = hist[i];
        base[i] = c ? atomicAdd(&bcnt[i], c) : 0u;
        hist[i] = 0;
    }
    __syncthreads();
    for (int i = lo + t; i < hi; i += 256) {
        unsigned s = (unsigned)src[i], d = (unsigned)dst[i];
        unsigned b = d >> 7;
        unsigned pos = base[b] + atomicAdd(&hist[b], 1u);
        if (pos < BCAP) bpair[(size_t)b * BCAP + pos] = s | ((d & 127u) << 16);
        else {
            unsigned o = atomicAdd(ovf_cnt, 1u);
            if (o < OVCAP) ovf[o] = make_uint2(s, d);
        }
    }
}

__global__ __launch_bounds__(256) void bucket_count_kernel(
    const unsigned* __restrict__ bcnt, const unsigned* __restrict__ bpair,
    const unsigned* __restrict__ ovf_cnt, const uint2* __restrict__ ovf,
    unsigned* __restrict__ counts, int n)
{
    __shared__ unsigned lc[128];
    const int b = blockIdx.x, base = b << 7;
    if (threadIdx.x < 128) lc[threadIdx.x] = 0;
    __syncthreads();
    unsigned bc = bcnt[b];
    int cnt = (int)(bc < BCAP ? bc : BCAP);
    for (int k = threadIdx.x; k < cnt; k += 256)
        atomicAdd(&lc[bpair[(size_t)b * BCAP + k] >> 16], 1u);
    unsigned oc_u = *ovf_cnt;
    int oc = (int)(oc_u < OVCAP ? oc_u : OVCAP);
    for (int k = threadIdx.x; k < oc; k += 256) {
        uint2 pp = ovf[k];
        if ((int)(pp.y >> 7) == b) atomicAdd(&lc[pp.y & 127u], 1u);
    }
    __syncthreads();
    int i = base + threadIdx.x;
    if (threadIdx.x < 128 && i < n) counts[i] = lc[threadIdx.x];
}

__global__ __launch_bounds__(256) void scan_reduce_kernel(const unsigned* __restrict__ counts,
                                                          unsigned* __restrict__ partials, int n)
{
    __shared__ unsigned sm[256];
    int t = threadIdx.x;
    int i = blockIdx.x * 256 + t;
    unsigned v = (i < n) ? counts[i] : 0u;
    sm[t] = v;
    __syncthreads();
#pragma unroll
    for (int off = 128; off > 0; off >>= 1) {
        if (t < off) sm[t] += sm[t + off];
        __syncthreads();
    }
    if (t == 0) partials[blockIdx.x] = sm[0];
}

__global__ __launch_bounds__(256) void scan_partials_kernel(unsigned* __restrict__ partials,
                                                            unsigned* __restrict__ rs, int nb, int n)
{
    __shared__ unsigned sm[256];
    int t = threadIdx.x;
    unsigned v = (t < nb) ? partials[t] : 0u;
    sm[t] = v;
    __syncthreads();
#pragma unroll
    for (int off = 1; off < 256; off <<= 1) {
        unsigned u = (t >= off) ? sm[t - off] : 0u;
        __syncthreads();
        sm[t] += u;
        __syncthreads();
    }
    if (t < nb) partials[t] = sm[t] - v;
    if (t == 255) rs[n] = sm[255];
}

__global__ __launch_bounds__(256) void scan_write_kernel(const unsigned* __restrict__ counts,
                                                         const unsigned* __restrict__ partials,
                                                         unsigned* __restrict__ rs,
                                                         float* __restrict__ nrm, int n)
{
    __shared__ unsigned sm[256];
    int t = threadIdx.x;
    int i = blockIdx.x * 256 + t;
    unsigned c = (i < n) ? counts[i] : 0u;
    sm[t] = c;
    __syncthreads();
#pragma unroll
    for (int off = 1; off < 256; off <<= 1) {
        unsigned u = (t >= off) ? sm[t - off] : 0u;
        __syncthreads();
        sm[t] += u;
        __syncthreads();
    }
    if (i < n) {
        rs[i] = partials[blockIdx.x] + sm[t] - c;
        nrm[i] = rsqrtf((float)(c + 1u));
    }
}

__global__ __launch_bounds__(256) void bucket_place_kernel(
    const unsigned* __restrict__ bcnt, const unsigned* __restrict__ bpair,
    const unsigned* __restrict__ rs, unsigned* __restrict__ csr_src,
    unsigned* __restrict__ cursor, int n)
{
    __shared__ unsigned lc[128];
    __shared__ unsigned rbase[128];
    const int b = blockIdx.x, base = b << 7;
    if (threadIdx.x < 128) {
        lc[threadIdx.x] = 0;
        int i = base + threadIdx.x;
        rbase[threadIdx.x] = (i < n) ? rs[i] : 0u;
    }
    __syncthreads();
    unsigned bc = bcnt[b];
    int cnt = (int)(bc < BCAP ? bc : BCAP);
    for (int k = threadIdx.x; k < cnt; k += 256) {
        unsigned v = bpair[(size_t)b * BCAP + k];
        unsigned ld = v >> 16;
        unsigned r = atomicAdd(&lc[ld], 1u);
        csr_src[rbase[ld] + r] = v & 0xFFFFu;
    }
    __syncthreads();
    int i = base + threadIdx.x;
    if (threadIdx.x < 128 && i < n) cursor[i] = rbase[threadIdx.x] + lc[threadIdx.x];
}

__global__ void overflow_fill_kernel(const unsigned* __restrict__ ovf_cnt,
                                     const uint2* __restrict__ ovf,
                                     unsigned* __restrict__ cursor,
                                     unsigned* __restrict__ csr_src)
{
    unsigned oc_u = *ovf_cnt;
    int oc = (int)(oc_u < OVCAP ? oc_u : OVCAP);
    for (int k = threadIdx.x; k < oc; k += 256) {
        uint2 pp = ovf[k];
        unsigned pos = atomicAdd(&cursor[pp.y], 1u);
        csr_src[pos] = pp.x;
    }
}

// -------- fused layer-1 aggregation: combined h1g row gather ----------------
#define CAP1 96
__global__ __launch_bounds__(256) void agg1_fused_kernel(
    const unsigned* __restrict__ h1g,
    const float* __restrict__ as1, const float* __restrict__ ad1,
    const float* __restrict__ nrm,
    const unsigned* __restrict__ rs, const unsigned* __restrict__ csr_src,
    const float* __restrict__ gat_b1, const float* __restrict__ gcn_b1,
    unsigned* __restrict__ xgb, unsigned* __restrict__ gaccb, int n)
{
    __shared__ uint2 scA[4][CAP1];
    __shared__ float w4[4][CAP1][4];
    const int wid = threadIdx.x >> 6;
    const int lane = threadIdx.x & 63;
    const int i = blockIdx.x * 4 + wid;
    if (i >= n) return;
    const unsigned beg = rs[i];
    const int deg = (int)(rs[i + 1] - beg);
    const float4* as1v = (const float4*)as1;
    float4 av = as1v[i];
    float4 dv = ((const float4*)ad1)[i];
    const float ni = nrm[i];
    float4 ese = make_float4(__expf(leakyf(av.x + dv.x)), __expf(leakyf(av.y + dv.y)),
                             __expf(leakyf(av.z + dv.z)), __expf(leakyf(av.w + dv.w)));
    float s0 = 0.f, s1 = 0.f, s2 = 0.f, s3 = 0.f;
    for (int k = lane; k < deg; k += 64) {
        unsigned s = csr_src[beg + k];
        float4 a = as1v[s];
        float w0 = __expf(leakyf(a.x + dv.x)), w1 = __expf(leakyf(a.y + dv.y));
        float w2 = __expf(leakyf(a.z + dv.z)), w3 = __expf(leakyf(a.w + dv.w));
        if (k < CAP1) {
            scA[wid][k] = make_uint2(s, __float_as_uint(nrm[s]));
            w4[wid][k][0] = w0; w4[wid][k][1] = w1;
            w4[wid][k][2] = w2; w4[wid][k][3] = w3;
        }
        s0 += w0; s1 += w1; s2 += w2; s3 += w3;
    }
    if (lane == 0) { s0 += ese.x; s1 += ese.y; s2 += ese.z; s3 += ese.w; }
    s0 = wred_sum(s0); s1 = wred_sum(s1); s2 = wred_sum(s2); s3 = wred_sum(s3);
    __threadfence_block();
    const int h = lane >> 4;
    const float advh = sel4(dv, h);
    const float ssh  = sel4(make_float4(s0, s1, s2, s3), h);
    const float wself = sel4(ese, h);
    const bool gact = lane < 32;
    const unsigned short* h1s = (const unsigned short*)h1g;
    float2 hv = unpack2_bf16(h1g[(size_t)i * 80 + lane]);
    float2 acc = make_float2(hv.x * wself, hv.y * wself);
    float gacc = gact ? bf2f(h1s[(size_t)i * 160 + 128 + lane]) * ni * ni : 0.f;
    const int dcB = deg < CAP1 ? deg : CAP1;
    int j = 0;
    for (; j + 4 <= dcB; j += 4) {
        uint2 sc[4]; float ww[4];
#pragma unroll
        for (int t = 0; t < 4; ++t) {
            sc[t] = scA[wid][j + t];
            ww[t] = w4[wid][j + t][h];
        }
        unsigned pv[4];
#pragma unroll
        for (int t = 0; t < 4; ++t) pv[t] = h1g[(size_t)sc[t].x * 80 + lane];
        float gv[4];
        if (gact) {
#pragma unroll
            for (int t = 0; t < 4; ++t) gv[t] = bf2f(h1s[(size_t)sc[t].x * 160 + 128 + lane]);
        }
#pragma unroll
        for (int t = 0; t < 4; ++t) {
            float2 v = unpack2_bf16(pv[t]);
            acc.x = fmaf(v.x, ww[t], acc.x);
            acc.y = fmaf(v.y, ww[t], acc.y);
            if (gact) gacc = fmaf(gv[t], __uint_as_float(sc[t].y) * ni, gacc);
        }
    }
    for (; j < dcB; ++j) {
        uint2 sc = scA[wid][j];
        float w = w4[wid][j][h];
        float2 v = unpack2_bf16(h1g[(size_t)sc.x * 80 + lane]);
        acc.x = fmaf(v.x, w, acc.x);
        acc.y = fmaf(v.y, w, acc.y);
        if (gact) gacc = fmaf(bf2f(h1s[(size_t)sc.x * 160 + 128 + lane]),
                              __uint_as_float(sc.y) * ni, gacc);
    }
    for (; j < deg; ++j) {                 // overflow (deg > CAP1)
        unsigned s = csr_src[beg + j];
        float4 a = as1v[s];
        float w = __expf(leakyf(sel4(a, h) + advh));
        float c = nrm[s];
        float2 v = unpack2_bf16(h1g[(size_t)s * 80 + lane]);
        acc.x = fmaf(v.x, w, acc.x);
        acc.y = fmaf(v.y, w, acc.y);
        if (gact) gacc = fmaf(bf2f(h1s[(size_t)s * 160 + 128 + lane]), c * ni, gacc);
    }
    float inv = 1.f / ssh;
    int c0 = 2 * lane;
    float o0 = acc.x * inv + gat_b1[c0];
    float o1 = acc.y * inv + gat_b1[c0 + 1];
    o0 = o0 > 0.f ? o0 : __expf(o0) - 1.f;
    o1 = o1 > 0.f ? o1 : __expf(o1) - 1.f;
    xgb[(size_t)i * 64 + lane] = pack2_bf16(o0, o1);
    float go = gact ? fmaxf(gacc + gcn_b1[lane], 0.f) : 0.f;
    float gp = __shfl_xor(go, 1, 64);
    if (gact && (lane & 1) == 0)
        gaccb[(size_t)i * 16 + (lane >> 1)] = pack2_bf16(go, gp);
}

// ---- merged layer-2 GEMMs (gcn K=32 + gat K=128) + logits2 epilogue --------
__global__ __launch_bounds__(320) void gemm2_fused_kernel(
    const unsigned* __restrict__ xgb, const unsigned* __restrict__ gaccb,
    const float* __restrict__ Wgat, const float* __restrict__ Wgcn,
    const float* __restrict__ aw_s, const float* __restrict__ aw_d,
    unsigned* __restrict__ hg_b, float* __restrict__ as2, float* __restrict__ ad2, int n)
{
    constexpr int BN = 128, NT = 320, CG = 10;
    __shared__ float smem[32 * 132 + 32 * 40];
    float* Xs = smem;
    float* Ws = smem + 32 * 132;
    const int tid = threadIdx.x;
    const int cg = tid % CG, ng = tid / CG;
    const int node0 = blockIdx.x * BN;

    // ---- part 1: gcn half (K = 32) ----
    {
        float acc[4][4] = {};
        for (int idx = tid; idx < BN * 4; idx += NT) {
            int nd = idx >> 2, kq = idx & 3;
            int gnode = node0 + nd;
            uint4 v = (gnode < n) ? *(const uint4*)&gaccb[(size_t)gnode * 16 + kq * 4]
                                  : make_uint4(0u, 0u, 0u, 0u);
            float2 a = unpack2_bf16(v.x), b = unpack2_bf16(v.y);
            float2 c = unpack2_bf16(v.z), d = unpack2_bf16(v.w);
            Xs[(kq * 8 + 0) * 132 + nd] = a.x; Xs[(kq * 8 + 1) * 132 + nd] = a.y;
            Xs[(kq * 8 + 2) * 132 + nd] = b.x; Xs[(kq * 8 + 3) * 132 + nd] = b.y;
            Xs[(kq * 8 + 4) * 132 + nd] = c.x; Xs[(kq * 8 + 5) * 132 + nd] = c.y;
            Xs[(kq * 8 + 6) * 132 + nd] = d.x; Xs[(kq * 8 + 7) * 132 + nd] = d.y;
        }
        for (int idx = tid; idx < 32 * CG; idx += NT) {
            int kk = idx / CG, cq = idx % CG;
            *(float4*)&Ws[kk * 40 + cq * 4] = *(const float4*)&Wgcn[(size_t)kk * 40 + cq * 4];
        }
        __syncthreads();
#pragma unroll
        for (int k = 0; k < 32; ++k) {
            float4 xv = *(const float4*)&Xs[k * 132 + ng * 4];
            float4 wv = *(const float4*)&Ws[k * 40 + cg * 4];
            float xa[4] = {xv.x, xv.y, xv.z, xv.w};
            float wa[4] = {wv.x, wv.y, wv.z, wv.w};
#pragma unroll
            for (int j = 0; j < 4; ++j)
#pragma unroll
                for (int c = 0; c < 4; ++c)
                    acc[j][c] = fmaf(xa[j], wa[c], acc[j][c]);
        }
        __syncthreads();
#pragma unroll
        for (int j = 0; j < 4; ++j) {
            int gnode = node0 + ng * 4 + j;
            if (gnode < n) {
                uint2 pb = make_uint2(pack2_bf16(acc[j][0], acc[j][1]),
                                      pack2_bf16(acc[j][2], acc[j][3]));
                *(uint2*)&hg_b[(size_t)gnode * 40 + 20 + cg * 2] = pb;
            }
        }
    }

    // ---- part 2: gat half (K = 128) + logits2 ----
    float acc[4][4] = {};
    for (int kb = 0; kb < 128; kb += 32) {
        for (int idx = tid; idx < BN * 4; idx += NT) {
            int nd = idx >> 2, kq = idx & 3;
            int gnode = node0 + nd;
            uint4 v = (gnode < n) ? *(const uint4*)&xgb[(size_t)gnode * 64 + kb / 2 + kq * 4]
                                  : make_uint4(0u, 0u, 0u, 0u);
            float2 a = unpack2_bf16(v.x), b = unpack2_bf16(v.y);
            float2 c = unpack2_bf16(v.z), d = unpack2_bf16(v.w);
            Xs[(kq * 8 + 0) * 132 + nd] = a.x; Xs[(kq * 8 + 1) * 132 + nd] = a.y;
            Xs[(kq * 8 + 2) * 132 + nd] = b.x; Xs[(kq * 8 + 3) * 132 + nd] = b.y;
            Xs[(kq * 8 + 4) * 132 + nd] = c.x; Xs[(kq * 8 + 5) * 132 + nd] = c.y;
            Xs[(kq * 8 + 6) * 132 + nd] = d.x; Xs[(kq * 8 + 7) * 132 + nd] = d.y;
        }
        for (int idx = tid; idx < 32 * CG; idx += NT) {
            int kk = idx / CG, cq = idx % CG;
            *(float4*)&Ws[kk * 40 + cq * 4] = *(const float4*)&Wgat[(size_t)(kb + kk) * 40 + cq * 4];
        }
        __syncthreads();
#pragma unroll
        for (int k = 0; k < 32; ++k) {
            float4 xv = *(const float4*)&Xs[k * 132 + ng * 4];
            float4 wv = *(const float4*)&Ws[k * 40 + cg * 4];
            float xa[4] = {xv.x, xv.y, xv.z, xv.w};
            float wa[4] = {wv.x, wv.y, wv.z, wv.w};
#pragma unroll
            for (int j = 0; j < 4; ++j)
#pragma unroll
                for (int c = 0; c < 4; ++c)
                    acc[j][c] = fmaf(xa[j], wa[c], acc[j][c]);
        }
        __syncthreads();
    }

    float* Ct  = smem;              // [128][41]
    float* sww = smem + 128 * 41;
    float* dww = sww + 40;
#pragma unroll
    for (int j = 0; j < 4; ++j) {
        int gnode = node0 + ng * 4 + j;
        if (gnode < n) {
            uint2 pb = make_uint2(pack2_bf16(acc[j][0], acc[j][1]),
                                  pack2_bf16(acc[j][2], acc[j][3]));
            *(uint2*)&hg_b[(size_t)gnode * 40 + cg * 2] = pb;
        }
#pragma unroll
        for (int c = 0; c < 4; ++c)
            Ct[(ng * 4 + j) * 41 + cg * 4 + c] = acc[j][c];
    }
    if (tid < 40) { sww[tid] = aw_s[tid]; dww[tid] = aw_d[tid]; }
    __syncthreads();
    if (tid < 128) {
        int gnode = node0 + tid;
        if (gnode < n) {
            float s = 0.f, d = 0.f;
#pragma unroll
            for (int c = 0; c < 40; ++c) {
                float v = Ct[tid * 41 + c];
                s = fmaf(v, sww[c], s);
                d = fmaf(v, dww[c], d);
            }
            as2[gnode] = s;
            ad2[gnode] = d;
        }
    }
}

// ---------------- fused layer-2 aggregation -> catb (bf16) ------------------
#define CAP2 128
__global__ __launch_bounds__(256) void agg2_fused_kernel(
    const unsigned* __restrict__ hg_b, const float* __restrict__ as2,
    const float* __restrict__ ad2, const float* __restrict__ nrm,
    const unsigned* __restrict__ rs, const unsigned* __restrict__ csr_src,
    const float* __restrict__ gat_b2, const float* __restrict__ gcn_b2,
    const float* __restrict__ wc_p, const float* __restrict__ wt_p,
    unsigned* __restrict__ catb, int n)
{
    __shared__ unsigned sidx[4][CAP2];
    __shared__ float    wgt[4][CAP2];
    __shared__ float    cf [4][CAP2];
    const int wid = threadIdx.x >> 6;
    const int lane = threadIdx.x & 63;
    const int i = blockIdx.x * 4 + wid;
    if (i >= n) return;
    const unsigned beg = rs[i];
    const int deg = (int)(rs[i + 1] - beg);
    const float adv = ad2[i];
    const float eself = __expf(leakyf(as2[i] + adv));
    const float ni = nrm[i];
    float ssum = (lane == 0) ? eself : 0.f;
    for (int k = lane; k < deg; k += 64) {
        unsigned s = csr_src[beg + k];
        float w = __expf(leakyf(as2[s] + adv));
        if (k < CAP2) { sidx[wid][k] = s; wgt[wid][k] = w; cf[wid][k] = nrm[s]; }
        ssum += w;
    }
    ssum = wred_sum(ssum);
    __threadfence_block();
    const bool act   = lane < 40;
    const bool isgat = lane < 20;
    const float selfw = isgat ? eself : ni * ni;
    float2 acc = make_float2(0.f, 0.f);
    if (act) {
        float2 v = unpack2_bf16(hg_b[(size_t)i * 40 + lane]);
        acc.x = v.x * selfw; acc.y = v.y * selfw;
    }
    const int dcB = deg < CAP2 ? deg : CAP2;
    int j = 0;
    for (; j + 4 <= dcB; j += 4) {
        unsigned ss[4]; float ww[4];
#pragma unroll
        for (int t = 0; t < 4; ++t) {
            ss[t] = sidx[wid][j + t];
            ww[t] = isgat ? wgt[wid][j + t] : cf[wid][j + t] * ni;
        }
        if (act) {
#pragma unroll
            for (int t = 0; t < 4; ++t) {
                float2 v = unpack2_bf16(hg_b[(size_t)ss[t] * 40 + lane]);
                acc.x = fmaf(v.x, ww[t], acc.x);
                acc.y = fmaf(v.y, ww[t], acc.y);
            }
        }
    }
    for (; j < dcB; ++j) {
        unsigned s = sidx[wid][j];
        float w = isgat ? wgt[wid][j] : cf[wid][j] * ni;
        if (act) {
            float2 v = unpack2_bf16(hg_b[(size_t)s * 40 + lane]);
            acc.x = fmaf(v.x, w, acc.x); acc.y = fmaf(v.y, w, acc.y);
        }
    }
    for (; j < deg; ++j) {
        unsigned s = csr_src[beg + j];
        float w = isgat ? __expf(leakyf(as2[s] + adv)) : nrm[s] * ni;
        if (act) {
            float2 v = unpack2_bf16(hg_b[(size_t)s * 40 + lane]);
            acc.x = fmaf(v.x, w, acc.x); acc.y = fmaf(v.y, w, acc.y);
        }
    }
    if (act) {
        if (isgat) {
            float inv = 1.f / ssum, wt = *wt_p;
            int c0 = 2 * lane;
            catb[(size_t)i * 40 + 20 + lane] =
                pack2_bf16((acc.x * inv + gat_b2[c0]) * wt,
                           (acc.y * inv + gat_b2[c0 + 1]) * wt);
        } else {
            float wc = *wc_p;
            int c0 = 2 * (lane - 20);
            catb[(size_t)i * 40 + (lane - 20)] =
                pack2_bf16((acc.x + gcn_b2[c0]) * wc,
                           (acc.y + gcn_b2[c0 + 1]) * wc);
        }
    }
}

// ---------------- head: out[n,40] = catb(bf16,[n,80]) @ lin_W + lin_b -------
__global__ __launch_bounds__(320) void gemm_head_kernel(
    const unsigned* __restrict__ catb, const float* __restrict__ W,
    const float* __restrict__ bias, float* __restrict__ out, int n)
{
    constexpr int BN = 128, NT = 320, CG = 10, BK = 40;
    __shared__ float Xs[BK][BN + 4];
    __shared__ float Ws[BK][40];
    const int tid = threadIdx.x;
    const int cg = tid % CG, ng = tid / CG;
    const int node0 = blockIdx.x * BN;
    float acc[4][4] = {};

    for (int kb = 0; kb < 80; kb += BK) {
        for (int idx = tid; idx < BN * 5; idx += NT) {     // 5 uint4 per node per tile
            int nd = idx / 5, kq = idx - nd * 5;
            int gnode = node0 + nd;
            uint4 v = (gnode < n) ? *(const uint4*)&catb[(size_t)gnode * 40 + kb / 2 + kq * 4]
                                  : make_uint4(0u, 0u, 0u, 0u);
            float2 a = unpack2_bf16(v.x), b = unpack2_bf16(v.y);
            float2 c = unpack2_bf16(v.z), d = unpack2_bf16(v.w);
            Xs[kq * 8 + 0][nd] = a.x; Xs[kq * 8 + 1][nd] = a.y;
            Xs[kq * 8 + 2][nd] = b.x; Xs[kq * 8 + 3][nd] = b.y;
            Xs[kq * 8 + 4][nd] = c.x; Xs[kq * 8 + 5][nd] = c.y;
            Xs[kq * 8 + 6][nd] = d.x; Xs[kq * 8 + 7][nd] = d.y;
        }
        for (int idx = tid; idx < BK * CG; idx += NT) {
            int kk = idx / CG, cq = idx % CG;
            *(float4*)&Ws[kk][cq * 4] = *(const float4*)&W[(size_t)(kb + kk) * 40 + cq * 4];
        }
        __syncthreads();
#pragma unroll
        for (int k = 0; k < BK; ++k) {
            float4 xv = *(const float4*)&Xs[k][ng * 4];
            float4 wv = *(const float4*)&Ws[k][cg * 4];
            float xa[4] = {xv.x, xv.y, xv.z, xv.w};
            float wa[4] = {wv.x, wv.y, wv.z, wv.w};
#pragma unroll
            for (int j = 0; j < 4; ++j)
#pragma unroll
                for (int c = 0; c < 4; ++c)
                    acc[j][c] = fmaf(xa[j], wa[c], acc[j][c]);
        }
        __syncthreads();
    }

    float4 bv = *(const float4*)&bias[cg * 4];
#pragma unroll
    for (int j = 0; j < 4; ++j) {
        int gnode = node0 + ng * 4 + j;
        if (gnode < n) {
            float4 o = make_float4(acc[j][0] + bv.x, acc[j][1] + bv.y,
                                   acc[j][2] + bv.z, acc[j][3] + bv.w);
            *(float4*)&out[(size_t)gnode * 40 + cg * 4] = o;
        }
    }
}

// ---------------- host ------------------------------------------------------
extern "C" void kernel_launch(void* const* d_in, const int* in_sizes, int n_in,
                              void* d_out, int out_size, void* d_ws, size_t ws_size,
                              hipStream_t stream)
{
    const float* x        = (const float*)d_in[0];
    const int*   eidx     = (const int*)d_in[1];
    const float* gat_W1   = (const float*)d_in[2];
    const float* att_s1   = (const float*)d_in[3];
    const float* att_d1   = (const float*)d_in[4];
    const float* gat_b1   = (const float*)d_in[5];
    const float* gat_W2   = (const float*)d_in[6];
    const float* att_s2   = (const float*)d_in[7];
    const float* att_d2   = (const float*)d_in[8];
    const float* gat_b2   = (const float*)d_in[9];
    const float* gcn_W1   = (const float*)d_in[10];
    const float* gcn_b1   = (const float*)d_in[11];
    const float* gcn_W2   = (const float*)d_in[12];
    const float* gcn_b2   = (const float*)d_in[13];
    const float* lin_W    = (const float*)d_in[14];
    const float* lin_b    = (const float*)d_in[15];
    const float* wc_p     = (const float*)d_in[16];
    const float* wt_p     = (const float*)d_in[17];

    const int n = in_sizes[0] / F_IN;      // 50000
    const int e = in_sizes[1] / 2;         // 800000
    const int* src = eidx;
    const int* dst = eidx + e;
    const int NBUCK = (n + 127) >> 7;      // 391

    char* p = (char*)d_ws;
    auto alloc = [&](size_t bytes) -> void* {
        void* r = (void*)p;
        p += (bytes + 255) & ~(size_t)255;
        return r;
    };
    unsigned* counts  = (unsigned*)alloc((size_t)n * 4);
    unsigned* rs      = (unsigned*)alloc((size_t)(n + 1) * 4);
    unsigned* cursor  = (unsigned*)alloc((size_t)n * 4);
    unsigned* partials= (unsigned*)alloc(256 * 4);
    unsigned* bcnt    = (unsigned*)alloc((size_t)(NBUCK + 1) * 4);
    unsigned* csr_src = (unsigned*)alloc((size_t)e * 4);
    uint4*    wbf     = (uint4*)alloc(40 * 64 * 16);
    float* nrm     = (float*)alloc((size_t)n * 4);
    float* as1     = (float*)alloc((size_t)n * 4 * 4);
    float* ad1     = (float*)alloc((size_t)n * 4 * 4);
    float* as2     = (float*)alloc((size_t)n * 4);
    float* ad2     = (float*)alloc((size_t)n * 4);
    unsigned* regA = (unsigned*)alloc((size_t)n * 80 * 4); // bpair/ovf -> h1g -> catb
    unsigned* hg_b = (unsigned*)alloc((size_t)n * 40 * 4);
    unsigned* xgb  = (unsigned*)alloc((size_t)n * 64 * 4);
    unsigned* gaccb= (unsigned*)alloc((size_t)n * 16 * 4);
    // aliases with disjoint lifetimes (stream-ordered):
    unsigned* bpair = regA;
    uint2*    ovf   = (uint2*)(bpair + (size_t)NBUCK * BCAP);
    unsigned* h1g   = regA;     // [n,80u] after CSR build; dead after agg1
    unsigned* catb  = regA;     // [n,40u] written by agg2 (after agg1)
    unsigned* ovf_cnt = bcnt + NBUCK;

    const int NB = (n + 255) / 256;
    const int WB = (n + 3) / 4;
    const int SB = (e + SCHUNK - 1) / SCHUNK;

    // ---- CSR build ----
    hipMemsetAsync(bcnt, 0, (size_t)(NBUCK + 1) * 4, stream);
    bucket_scatter_kernel<<<SB, 256, 0, stream>>>(src, dst, bcnt, bpair, ovf_cnt, ovf, e, NBUCK);
    bucket_count_kernel<<<NBUCK, 256, 0, stream>>>(bcnt, bpair, ovf_cnt, ovf, counts, n);
    scan_reduce_kernel<<<NB, 256, 0, stream>>>(counts, partials, n);
    scan_partials_kernel<<<1, 256, 0, stream>>>(partials, rs, NB, n);
    scan_write_kernel<<<NB, 256, 0, stream>>>(counts, partials, rs, nrm, n);
    bucket_place_kernel<<<NBUCK, 256, 0, stream>>>(bcnt, bpair, rs, csr_src, cursor, n);
    overflow_fill_kernel<<<1, 256, 0, stream>>>(ovf_cnt, ovf, cursor, csr_src);

    // ---- W pre-pack + MFMA first-layer GEMM (combined h1g + logits1) ----
    wb_prep_kernel<<<40, 64, 0, stream>>>(gat_W1, gcn_W1, wbf);
    gemm1_mfma_kernel<<<(n + 63) / 64, 256, 0, stream>>>(x, wbf, att_s1, att_d1,
                                                         h1g, as1, ad1, n);

    // ---- fused layer-1 aggregation (one combined-row walk) ----
    agg1_fused_kernel<<<WB, 256, 0, stream>>>(h1g, as1, ad1, nrm, rs, csr_src,
                                              gat_b1, gcn_b1, xgb, gaccb, n);

    // ---- merged layer-2 GEMMs (+logits2) -> hg_b ----
    gemm2_fused_kernel<<<(n + 127) / 128, 320, 0, stream>>>(xgb, gaccb, gat_W2, gcn_W2,
                                                            att_s2, att_d2, hg_b, as2, ad2, n);

    // ---- fused layer-2 aggregation -> catb (bf16) ----
    agg2_fused_kernel<<<WB, 256, 0, stream>>>(hg_b, as2, ad2, nrm, rs, csr_src,
                                              gat_b2, gcn_b2, wc_p, wt_p, catb, n);

    // ---- head ----
    gemm_head_kernel<<<(n + 127) / 128, 320, 0, stream>>>(catb, lin_W, lin_b, (float*)d_out, n);
}

// Round 15
// 305.513 us; speedup vs baseline: 1.0259x; 1.0259x over previous
//
#include <hip/hip_runtime.h>
#include <math.h>

#define F_IN   128
#define HIDC   32
#define NHEAD  4
#define CDIM   40
#define NEG_SLOPE 0.2f
#define BCAP   4096
#define OVCAP  16384
#define SCHUNK 4096

typedef __attribute__((ext_vector_type(8))) short bf16x8;   // 8 bf16 = 4 VGPRs
typedef __attribute__((ext_vector_type(4))) float f32x4;    // MFMA C/D

__device__ __forceinline__ float leakyf(float x) { return x > 0.f ? x : NEG_SLOPE * x; }

__device__ __forceinline__ float wred_sum(float v) {
#pragma unroll
    for (int o = 32; o > 0; o >>= 1) v += __shfl_xor(v, o, 64);
    return v;
}
__device__ __forceinline__ float sel4(float4 v, int h) {
    return (h == 0) ? v.x : (h == 1) ? v.y : (h == 2) ? v.z : v.w;
}
__device__ __forceinline__ unsigned pack2_bf16(float a, float b) {
    unsigned ua = __float_as_uint(a);
    unsigned ub = __float_as_uint(b);
    ua = (ua + 0x7FFFu + ((ua >> 16) & 1u)) >> 16;
    ub = (ub + 0x7FFFu + ((ub >> 16) & 1u)) >> 16;
    return ua | (ub << 16);
}
__device__ __forceinline__ float2 unpack2_bf16(unsigned p) {
    return make_float2(__uint_as_float(p << 16), __uint_as_float(p & 0xFFFF0000u));
}
__device__ __forceinline__ float bf2f(unsigned short u) {
    return __uint_as_float(((unsigned)u) << 16);
}

// ---- W pre-pack into MFMA B-fragment order --------------------------------
__global__ void wb_prep_kernel(const float* __restrict__ Wg, const float* __restrict__ Wc,
                               uint4* __restrict__ wbf)
{
    int b = blockIdx.x;            // nt*4 + ks, 0..39
    int lane = threadIdx.x;        // 0..63
    int nt = b >> 2, ks = b & 3;
    int c = nt * 16 + (lane & 15);
    int k0 = ks * 32 + (lane >> 4) * 8;
    unsigned u[4];
#pragma unroll
    for (int jj = 0; jj < 4; ++jj) {
        int k = k0 + 2 * jj;
        float a0 = (c < 128) ? Wg[(size_t)k * 128 + c] : Wc[(size_t)k * 32 + (c - 128)];
        float a1 = (c < 128) ? Wg[(size_t)(k + 1) * 128 + c] : Wc[(size_t)(k + 1) * 32 + (c - 128)];
        u[jj] = pack2_bf16(a0, a1);
    }
    wbf[(size_t)b * 64 + lane] = make_uint4(u[0], u[1], u[2], u[3]);
}

// ---- first-layer GEMM on MFMA; emits combined h1g[n,80u] + logits1 --------
__global__ __launch_bounds__(256) void gemm1_mfma_kernel(
    const float* __restrict__ X, const uint4* __restrict__ wbf,
    const float* __restrict__ aw_s, const float* __restrict__ aw_d,
    unsigned* __restrict__ h1g,
    float* __restrict__ as1, float* __restrict__ ad1, int n)
{
    __shared__ float Ct[64][164];
    __shared__ float sw[128], dw[128];
    const int tid = threadIdx.x;
    const int w = tid >> 6, lane = tid & 63;
    const int m = lane & 15, q = lane >> 4;
    const int node0 = blockIdx.x * 64;
    if (tid < 128) { sw[tid] = aw_s[tid]; dw[tid] = aw_d[tid]; }

    f32x4 acc[10];
#pragma unroll
    for (int t = 0; t < 10; ++t) acc[t] = (f32x4){0.f, 0.f, 0.f, 0.f};

    const int row = node0 + w * 16 + m;
    const bool rv = row < n;
#pragma unroll
    for (int ks = 0; ks < 4; ++ks) {
        uint4 pa = make_uint4(0u, 0u, 0u, 0u);
        if (rv) {
            const float* xr = X + (size_t)row * 128 + ks * 32 + q * 8;
            float4 a0 = *(const float4*)xr;
            float4 a1 = *(const float4*)(xr + 4);
            pa = make_uint4(pack2_bf16(a0.x, a0.y), pack2_bf16(a0.z, a0.w),
                            pack2_bf16(a1.x, a1.y), pack2_bf16(a1.z, a1.w));
        }
        bf16x8 af = *(bf16x8*)&pa;
#pragma unroll
        for (int nt = 0; nt < 10; ++nt) {
            uint4 pb = wbf[(size_t)(nt * 4 + ks) * 64 + lane];
            bf16x8 bfv = *(bf16x8*)&pb;
            acc[nt] = __builtin_amdgcn_mfma_f32_16x16x32_bf16(af, bfv, acc[nt], 0, 0, 0);
        }
    }
#pragma unroll
    for (int nt = 0; nt < 10; ++nt)
#pragma unroll
        for (int r = 0; r < 4; ++r)
            Ct[w * 16 + q * 4 + r][nt * 16 + m] = acc[nt][r];
    __syncthreads();

    for (int i = tid; i < 64 * 80; i += 256) {
        int nd = i / 80, u = i - nd * 80;
        int gn = node0 + nd;
        if (gn < n)
            h1g[(size_t)gn * 80 + u] = pack2_bf16(Ct[nd][2 * u], Ct[nd][2 * u + 1]);
    }
    {
        int nd = tid >> 2, h = tid & 3;
        int gn = node0 + nd;
        if (gn < n) {
            float s = 0.f, d = 0.f;
#pragma unroll
            for (int k = 0; k < HIDC; ++k) {
                float v = Ct[nd][h * HIDC + k];
                s = fmaf(v, sw[h * HIDC + k], s);
                d = fmaf(v, dw[h * HIDC + k], d);
            }
            as1[(size_t)gn * 4 + h] = s;
            ad1[(size_t)gn * 4 + h] = d;
        }
    }
}

// ---------------- CSR build: bucketed counting sort by dst ------------------
__global__ __launch_bounds__(256) void bucket_scatter_kernel(
    const int* __restrict__ src, const int* __restrict__ dst,
    unsigned* __restrict__ bcnt, unsigned* __restrict__ bpair,
    unsigned* __restrict__ ovf_cnt, uint2* __restrict__ ovf, int e, int nbuck)
{
    __shared__ unsigned hist[512];
    __shared__ unsigned base[512];
    const int t = threadIdx.x;
    const int lo = blockIdx.x * SCHUNK;
    const int hi = min(lo + SCHUNK, e);
    for (int i = t; i < nbuck; i += 256) hist[i] = 0;
    __syncthreads();
    for (int i = lo + t; i < hi; i += 256)
        atomicAdd(&hist[((unsigned)dst[i]) >> 7], 1u);
    __syncthreads();
    for (int i = t; i < nbuck; i += 256) {
        unsigned c = hist[i];
        base[i] = c ? atomicAdd(&bcnt[i], c) : 0u;
        hist[i] = 0;
    }
    __syncthreads();
    for (int i = lo + t; i < hi; i += 256) {
        unsigned s = (unsigned)src[i], d = (unsigned)dst[i];
        unsigned b = d >> 7;
        unsigned pos = base[b] + atomicAdd(&hist[b], 1u);
        if (pos < BCAP) bpair[(size_t)b * BCAP + pos] = s | ((d & 127u) << 16);
        else {
            unsigned o = atomicAdd(ovf_cnt, 1u);
            if (o < OVCAP) ovf[o] = make_uint2(s, d);
        }
    }
}

// exclusive prefix over the 391 bucket totals (1 block, 512 thr)
__global__ __launch_bounds__(512) void bucket_prefix_kernel(
    const unsigned* __restrict__ bcnt, unsigned* __restrict__ bprefix,
    unsigned* __restrict__ rs, int nbuck, int n, unsigned e)
{
    __shared__ unsigned sm[512];
    int t = threadIdx.x;
    unsigned v = (t < nbuck) ? bcnt[t] : 0u;
    sm[t] = v;
    __syncthreads();
#pragma unroll
    for (int off = 1; off < 512; off <<= 1) {
        unsigned u = (t >= off) ? sm[t - off] : 0u;
        __syncthreads();
        sm[t] += u;
        __syncthreads();
    }
    if (t < nbuck) bprefix[t] = sm[t] - v;     // exclusive
    if (t == 0) rs[n] = e;
}

// merged: histogram + local scan + rs/nrm write + placement (one bpair read)
__global__ __launch_bounds__(256) void bucket_build_kernel(
    const unsigned* __restrict__ bcnt, const unsigned* __restrict__ bpair,
    const unsigned* __restrict__ bprefix,
    const unsigned* __restrict__ ovf_cnt, const uint2* __restrict__ ovf,
    unsigned* __restrict__ rs, float* __restrict__ nrm,
    unsigned* __restrict__ csr_src, unsigned* __restrict__ cursor, int n)
{
    __shared__ unsigned sp[BCAP];            // staged bucket pairs (16 KB)
    __shared__ unsigned lc[128], ex[128], plc[128];
    const int b = blockIdx.x, base = b << 7;
    const int tid = threadIdx.x;
    if (tid < 128) { lc[tid] = 0; plc[tid] = 0; }
    __syncthreads();
    unsigned bc = bcnt[b];
    int cnt = (int)(bc < BCAP ? bc : BCAP);
    for (int k = tid; k < cnt; k += 256) {
        unsigned v = bpair[(size_t)b * BCAP + k];
        sp[k] = v;
        atomicAdd(&lc[v >> 16], 1u);
    }
    unsigned oc_u = *ovf_cnt;
    int oc = (int)(oc_u < OVCAP ? oc_u : OVCAP);
    for (int k = tid; k < oc; k += 256) {
        uint2 pp = ovf[k];
        if ((int)(pp.y >> 7) == b) atomicAdd(&lc[pp.y & 127u], 1u);
    }
    __syncthreads();
    // exclusive scan of lc into ex (all threads hit barriers)
    unsigned myc = (tid < 128) ? lc[tid] : 0u;
    if (tid < 128) ex[tid] = myc;
    __syncthreads();
#pragma unroll
    for (int off = 1; off < 128; off <<= 1) {
        unsigned u = (tid < 128 && tid >= off) ? ex[tid - off] : 0u;
        __syncthreads();
        if (tid < 128) ex[tid] += u;
        __syncthreads();
    }
    if (tid < 128) ex[tid] -= myc;           // exclusive
    __syncthreads();
    const unsigned bp = bprefix[b];
    if (tid < 128) {
        int i = base + tid;
        if (i < n) {
            rs[i]  = bp + ex[tid];
            nrm[i] = rsqrtf((float)(lc[tid] + 1u));
        }
    }
    __syncthreads();
    for (int k = tid; k < cnt; k += 256) {
        unsigned v = sp[k];
        unsigned ld = v >> 16;
        unsigned r = atomicAdd(&plc[ld], 1u);
        csr_src[bp + ex[ld] + r] = v & 0xFFFFu;
    }
    __syncthreads();
    if (tid < 128) {
        int i = base + tid;
        if (i < n) cursor[i] = bp + ex[tid] + plc[tid];
    }
}

__global__ void overflow_fill_kernel(const unsigned* __restrict__ ovf_cnt,
                                     const uint2* __restrict__ ovf,
                                     unsigned* __restrict__ cursor,
                                     unsigned* __restrict__ csr_src)
{
    unsigned oc_u = *ovf_cnt;
    int oc = (int)(oc_u < OVCAP ? oc_u : OVCAP);
    for (int k = threadIdx.x; k < oc; k += 256) {
        uint2 pp = ovf[k];
        unsigned pos = atomicAdd(&cursor[pp.y], 1u);
        csr_src[pos] = pp.x;
    }
}

// -------- fused layer-1 aggregation: combined h1g row gather ----------------
#define CAP1 96
__global__ __launch_bounds__(256) void agg1_fused_kernel(
    const unsigned* __restrict__ h1g,
    const float* __restrict__ as1, const float* __restrict__ ad1,
    const float* __restrict__ nrm,
    const unsigned* __restrict__ rs, const unsigned* __restrict__ csr_src,
    const float* __restrict__ gat_b1, const float* __restrict__ gcn_b1,
    unsigned* __restrict__ xgb, unsigned* __restrict__ gaccb, int n)
{
    __shared__ uint2 scA[4][CAP1];
    __shared__ float w4[4][CAP1][4];
    const int wid = threadIdx.x >> 6;
    const int lane = threadIdx.x & 63;
    const int i = blockIdx.x * 4 + wid;
    if (i >= n) return;
    const unsigned beg = rs[i];
    const int deg = (int)(rs[i + 1] - beg);
    const float4* as1v = (const float4*)as1;
    float4 av = as1v[i];
    float4 dv = ((const float4*)ad1)[i];
    const float ni = nrm[i];
    float4 ese = make_float4(__expf(leakyf(av.x + dv.x)), __expf(leakyf(av.y + dv.y)),
                             __expf(leakyf(av.z + dv.z)), __expf(leakyf(av.w + dv.w)));
    float s0 = 0.f, s1 = 0.f, s2 = 0.f, s3 = 0.f;
    for (int k = lane; k < deg; k += 64) {
        unsigned s = csr_src[beg + k];
        float4 a = as1v[s];
        float w0 = __expf(leakyf(a.x + dv.x)), w1 = __expf(leakyf(a.y + dv.y));
        float w2 = __expf(leakyf(a.z + dv.z)), w3 = __expf(leakyf(a.w + dv.w));
        if (k < CAP1) {
            scA[wid][k] = make_uint2(s, __float_as_uint(nrm[s]));
            w4[wid][k][0] = w0; w4[wid][k][1] = w1;
            w4[wid][k][2] = w2; w4[wid][k][3] = w3;
        }
        s0 += w0; s1 += w1; s2 += w2; s3 += w3;
    }
    if (lane == 0) { s0 += ese.x; s1 += ese.y; s2 += ese.z; s3 += ese.w; }
    s0 = wred_sum(s0); s1 = wred_sum(s1); s2 = wred_sum(s2); s3 = wred_sum(s3);
    __threadfence_block();
    const int h = lane >> 4;
    const float advh = sel4(dv, h);
    const float ssh  = sel4(make_float4(s0, s1, s2, s3), h);
    const float wself = sel4(ese, h);
    const bool gact = lane < 32;
    const unsigned short* h1s = (const unsigned short*)h1g;
    float2 hv = unpack2_bf16(h1g[(size_t)i * 80 + lane]);
    float2 acc = make_float2(hv.x * wself, hv.y * wself);
    float gacc = gact ? bf2f(h1s[(size_t)i * 160 + 128 + lane]) * ni * ni : 0.f;
    const int dcB = deg < CAP1 ? deg : CAP1;
    int j = 0;
    for (; j + 4 <= dcB; j += 4) {
        uint2 sc[4]; float ww[4];
#pragma unroll
        for (int t = 0; t < 4; ++t) {
            sc[t] = scA[wid][j + t];
            ww[t] = w4[wid][j + t][h];
        }
        unsigned pv[4];
#pragma unroll
        for (int t = 0; t < 4; ++t) pv[t] = h1g[(size_t)sc[t].x * 80 + lane];
        float gv[4];
        if (gact) {
#pragma unroll
            for (int t = 0; t < 4; ++t) gv[t] = bf2f(h1s[(size_t)sc[t].x * 160 + 128 + lane]);
        }
#pragma unroll
        for (int t = 0; t < 4; ++t) {
            float2 v = unpack2_bf16(pv[t]);
            acc.x = fmaf(v.x, ww[t], acc.x);
            acc.y = fmaf(v.y, ww[t], acc.y);
            if (gact) gacc = fmaf(gv[t], __uint_as_float(sc[t].y) * ni, gacc);
        }
    }
    for (; j < dcB; ++j) {
        uint2 sc = scA[wid][j];
        float w = w4[wid][j][h];
        float2 v = unpack2_bf16(h1g[(size_t)sc.x * 80 + lane]);
        acc.x = fmaf(v.x, w, acc.x);
        acc.y = fmaf(v.y, w, acc.y);
        if (gact) gacc = fmaf(bf2f(h1s[(size_t)sc.x * 160 + 128 + lane]),
                              __uint_as_float(sc.y) * ni, gacc);
    }
    for (; j < deg; ++j) {                 // overflow (deg > CAP1)
        unsigned s = csr_src[beg + j];
        float4 a = as1v[s];
        float w = __expf(leakyf(sel4(a, h) + advh));
        float c = nrm[s];
        float2 v = unpack2_bf16(h1g[(size_t)s * 80 + lane]);
        acc.x = fmaf(v.x, w, acc.x);
        acc.y = fmaf(v.y, w, acc.y);
        if (gact) gacc = fmaf(bf2f(h1s[(size_t)s * 160 + 128 + lane]), c * ni, gacc);
    }
    float inv = 1.f / ssh;
    int c0 = 2 * lane;
    float o0 = acc.x * inv + gat_b1[c0];
    float o1 = acc.y * inv + gat_b1[c0 + 1];
    o0 = o0 > 0.f ? o0 : __expf(o0) - 1.f;
    o1 = o1 > 0.f ? o1 : __expf(o1) - 1.f;
    xgb[(size_t)i * 64 + lane] = pack2_bf16(o0, o1);
    float go = gact ? fmaxf(gacc + gcn_b1[lane], 0.f) : 0.f;
    float gp = __shfl_xor(go, 1, 64);
    if (gact && (lane & 1) == 0)
        gaccb[(size_t)i * 16 + (lane >> 1)] = pack2_bf16(go, gp);
}

// ---- merged layer-2 GEMMs (gcn K=32 + gat K=128) + logits2 epilogue --------
__global__ __launch_bounds__(320) void gemm2_fused_kernel(
    const unsigned* __restrict__ xgb, const unsigned* __restrict__ gaccb,
    const float* __restrict__ Wgat, const float* __restrict__ Wgcn,
    const float* __restrict__ aw_s, const float* __restrict__ aw_d,
    unsigned* __restrict__ hg_b, float* __restrict__ as2, float* __restrict__ ad2, int n)
{
    constexpr int BN = 128, NT = 320, CG = 10;
    __shared__ float smem[32 * 132 + 32 * 40];
    float* Xs = smem;
    float* Ws = smem + 32 * 132;
    const int tid = threadIdx.x;
    const int cg = tid % CG, ng = tid / CG;
    const int node0 = blockIdx.x * BN;

    // ---- part 1: gcn half (K = 32) ----
    {
        float acc[4][4] = {};
        for (int idx = tid; idx < BN * 4; idx += NT) {
            int nd = idx >> 2, kq = idx & 3;
            int gnode = node0 + nd;
            uint4 v = (gnode < n) ? *(const uint4*)&gaccb[(size_t)gnode * 16 + kq * 4]
                                  : make_uint4(0u, 0u, 0u, 0u);
            float2 a = unpack2_bf16(v.x), b = unpack2_bf16(v.y);
            float2 c = unpack2_bf16(v.z), d = unpack2_bf16(v.w);
            Xs[(kq * 8 + 0) * 132 + nd] = a.x; Xs[(kq * 8 + 1) * 132 + nd] = a.y;
            Xs[(kq * 8 + 2) * 132 + nd] = b.x; Xs[(kq * 8 + 3) * 132 + nd] = b.y;
            Xs[(kq * 8 + 4) * 132 + nd] = c.x; Xs[(kq * 8 + 5) * 132 + nd] = c.y;
            Xs[(kq * 8 + 6) * 132 + nd] = d.x; Xs[(kq * 8 + 7) * 132 + nd] = d.y;
        }
        for (int idx = tid; idx < 32 * CG; idx += NT) {
            int kk = idx / CG, cq = idx % CG;
            *(float4*)&Ws[kk * 40 + cq * 4] = *(const float4*)&Wgcn[(size_t)kk * 40 + cq * 4];
        }
        __syncthreads();
#pragma unroll
        for (int k = 0; k < 32; ++k) {
            float4 xv = *(const float4*)&Xs[k * 132 + ng * 4];
            float4 wv = *(const float4*)&Ws[k * 40 + cg * 4];
            float xa[4] = {xv.x, xv.y, xv.z, xv.w};
            float wa[4] = {wv.x, wv.y, wv.z, wv.w};
#pragma unroll
            for (int j = 0; j < 4; ++j)
#pragma unroll
                for (int c = 0; c < 4; ++c)
                    acc[j][c] = fmaf(xa[j], wa[c], acc[j][c]);
        }
        __syncthreads();
#pragma unroll
        for (int j = 0; j < 4; ++j) {
            int gnode = node0 + ng * 4 + j;
            if (gnode < n) {
                uint2 pb = make_uint2(pack2_bf16(acc[j][0], acc[j][1]),
                                      pack2_bf16(acc[j][2], acc[j][3]));
                *(uint2*)&hg_b[(size_t)gnode * 40 + 20 + cg * 2] = pb;
            }
        }
    }

    // ---- part 2: gat half (K = 128) + logits2 ----
    float acc[4][4] = {};
    for (int kb = 0; kb < 128; kb += 32) {
        for (int idx = tid; idx < BN * 4; idx += NT) {
            int nd = idx >> 2, kq = idx & 3;
            int gnode = node0 + nd;
            uint4 v = (gnode < n) ? *(const uint4*)&xgb[(size_t)gnode * 64 + kb / 2 + kq * 4]
                                  : make_uint4(0u, 0u, 0u, 0u);
            float2 a = unpack2_bf16(v.x), b = unpack2_bf16(v.y);
            float2 c = unpack2_bf16(v.z), d = unpack2_bf16(v.w);
            Xs[(kq * 8 + 0) * 132 + nd] = a.x; Xs[(kq * 8 + 1) * 132 + nd] = a.y;
            Xs[(kq * 8 + 2) * 132 + nd] = b.x; Xs[(kq * 8 + 3) * 132 + nd] = b.y;
            Xs[(kq * 8 + 4) * 132 + nd] = c.x; Xs[(kq * 8 + 5) * 132 + nd] = c.y;
            Xs[(kq * 8 + 6) * 132 + nd] = d.x; Xs[(kq * 8 + 7) * 132 + nd] = d.y;
        }
        for (int idx = tid; idx < 32 * CG; idx += NT) {
            int kk = idx / CG, cq = idx % CG;
            *(float4*)&Ws[kk * 40 + cq * 4] = *(const float4*)&Wgat[(size_t)(kb + kk) * 40 + cq * 4];
        }
        __syncthreads();
#pragma unroll
        for (int k = 0; k < 32; ++k) {
            float4 xv = *(const float4*)&Xs[k * 132 + ng * 4];
            float4 wv = *(const float4*)&Ws[k * 40 + cg * 4];
            float xa[4] = {xv.x, xv.y, xv.z, xv.w};
            float wa[4] = {wv.x, wv.y, wv.z, wv.w};
#pragma unroll
            for (int j = 0; j < 4; ++j)
#pragma unroll
                for (int c = 0; c < 4; ++c)
                    acc[j][c] = fmaf(xa[j], wa[c], acc[j][c]);
        }
        __syncthreads();
    }

    float* Ct  = smem;              // [128][41]
    float* sww = smem + 128 * 41;
    float* dww = sww + 40;
#pragma unroll
    for (int j = 0; j < 4; ++j) {
        int gnode = node0 + ng * 4 + j;
        if (gnode < n) {
            uint2 pb = make_uint2(pack2_bf16(acc[j][0], acc[j][1]),
                                  pack2_bf16(acc[j][2], acc[j][3]));
            *(uint2*)&hg_b[(size_t)gnode * 40 + cg * 2] = pb;
        }
#pragma unroll
        for (int c = 0; c < 4; ++c)
            Ct[(ng * 4 + j) * 41 + cg * 4 + c] = acc[j][c];
    }
    if (tid < 40) { sww[tid] = aw_s[tid]; dww[tid] = aw_d[tid]; }
    __syncthreads();
    if (tid < 128) {
        int gnode = node0 + tid;
        if (gnode < n) {
            float s = 0.f, d = 0.f;
#pragma unroll
            for (int c = 0; c < 40; ++c) {
                float v = Ct[tid * 41 + c];
                s = fmaf(v, sww[c], s);
                d = fmaf(v, dww[c], d);
            }
            as2[gnode] = s;
            ad2[gnode] = d;
        }
    }
}

// ---------------- fused layer-2 aggregation -> catb (bf16) ------------------
#define CAP2 128
__global__ __launch_bounds__(256) void agg2_fused_kernel(
    const unsigned* __restrict__ hg_b, const float* __restrict__ as2,
    const float* __restrict__ ad2, const float* __restrict__ nrm,
    const unsigned* __restrict__ rs, const unsigned* __restrict__ csr_src,
    const float* __restrict__ gat_b2, const float* __restrict__ gcn_b2,
    const float* __restrict__ wc_p, const float* __restrict__ wt_p,
    unsigned* __restrict__ catb, int n)
{
    __shared__ unsigned sidx[4][CAP2];
    __shared__ float    wgt[4][CAP2];
    __shared__ float    cf [4][CAP2];
    const int wid = threadIdx.x >> 6;
    const int lane = threadIdx.x & 63;
    const int i = blockIdx.x * 4 + wid;
    if (i >= n) return;
    const unsigned beg = rs[i];
    const int deg = (int)(rs[i + 1] - beg);
    const float adv = ad2[i];
    const float eself = __expf(leakyf(as2[i] + adv));
    const float ni = nrm[i];
    float ssum = (lane == 0) ? eself : 0.f;
    for (int k = lane; k < deg; k += 64) {
        unsigned s = csr_src[beg + k];
        float w = __expf(leakyf(as2[s] + adv));
        if (k < CAP2) { sidx[wid][k] = s; wgt[wid][k] = w; cf[wid][k] = nrm[s]; }
        ssum += w;
    }
    ssum = wred_sum(ssum);
    __threadfence_block();
    const bool act   = lane < 40;
    const bool isgat = lane < 20;
    const float selfw = isgat ? eself : ni * ni;
    float2 acc = make_float2(0.f, 0.f);
    if (act) {
        float2 v = unpack2_bf16(hg_b[(size_t)i * 40 + lane]);
        acc.x = v.x * selfw; acc.y = v.y * selfw;
    }
    const int dcB = deg < CAP2 ? deg : CAP2;
    int j = 0;
    for (; j + 4 <= dcB; j += 4) {
        unsigned ss[4]; float ww[4];
#pragma unroll
        for (int t = 0; t < 4; ++t) {
            ss[t] = sidx[wid][j + t];
            ww[t] = isgat ? wgt[wid][j + t] : cf[wid][j + t] * ni;
        }
        if (act) {
#pragma unroll
            for (int t = 0; t < 4; ++t) {
                float2 v = unpack2_bf16(hg_b[(size_t)ss[t] * 40 + lane]);
                acc.x = fmaf(v.x, ww[t], acc.x);
                acc.y = fmaf(v.y, ww[t], acc.y);
            }
        }
    }
    for (; j < dcB; ++j) {
        unsigned s = sidx[wid][j];
        float w = isgat ? wgt[wid][j] : cf[wid][j] * ni;
        if (act) {
            float2 v = unpack2_bf16(hg_b[(size_t)s * 40 + lane]);
            acc.x = fmaf(v.x, w, acc.x); acc.y = fmaf(v.y, w, acc.y);
        }
    }
    for (; j < deg; ++j) {
        unsigned s = csr_src[beg + j];
        float w = isgat ? __expf(leakyf(as2[s] + adv)) : nrm[s] * ni;
        if (act) {
            float2 v = unpack2_bf16(hg_b[(size_t)s * 40 + lane]);
            acc.x = fmaf(v.x, w, acc.x); acc.y = fmaf(v.y, w, acc.y);
        }
    }
    if (act) {
        if (isgat) {
            float inv = 1.f / ssum, wt = *wt_p;
            int c0 = 2 * lane;
            catb[(size_t)i * 40 + 20 + lane] =
                pack2_bf16((acc.x * inv + gat_b2[c0]) * wt,
                           (acc.y * inv + gat_b2[c0 + 1]) * wt);
        } else {
            float wc = *wc_p;
            int c0 = 2 * (lane - 20);
            catb[(size_t)i * 40 + (lane - 20)] =
                pack2_bf16((acc.x + gcn_b2[c0]) * wc,
                           (acc.y + gcn_b2[c0 + 1]) * wc);
        }
    }
}

// ---------------- head: out[n,40] = catb(bf16,[n,80]) @ lin_W + lin_b -------
__global__ __launch_bounds__(320) void gemm_head_kernel(
    const unsigned* __restrict__ catb, const float* __restrict__ W,
    const float* __restrict__ bias, float* __restrict__ out, int n)
{
    constexpr int BN = 128, NT = 320, CG = 10, BK = 40;
    __shared__ float Xs[BK][BN + 4];
    __shared__ float Ws[BK][40];
    const int tid = threadIdx.x;
    const int cg = tid % CG, ng = tid / CG;
    const int node0 = blockIdx.x * BN;
    float acc[4][4] = {};

    for (int kb = 0; kb < 80; kb += BK) {
        for (int idx = tid; idx < BN * 5; idx += NT) {     // 5 uint4 per node per tile
            int nd = idx / 5, kq = idx - nd * 5;
            int gnode = node0 + nd;
            uint4 v = (gnode < n) ? *(const uint4*)&catb[(size_t)gnode * 40 + kb / 2 + kq * 4]
                                  : make_uint4(0u, 0u, 0u, 0u);
            float2 a = unpack2_bf16(v.x), b = unpack2_bf16(v.y);
            float2 c = unpack2_bf16(v.z), d = unpack2_bf16(v.w);
            Xs[kq * 8 + 0][nd] = a.x; Xs[kq * 8 + 1][nd] = a.y;
            Xs[kq * 8 + 2][nd] = b.x; Xs[kq * 8 + 3][nd] = b.y;
            Xs[kq * 8 + 4][nd] = c.x; Xs[kq * 8 + 5][nd] = c.y;
            Xs[kq * 8 + 6][nd] = d.x; Xs[kq * 8 + 7][nd] = d.y;
        }
        for (int idx = tid; idx < BK * CG; idx += NT) {
            int kk = idx / CG, cq = idx % CG;
            *(float4*)&Ws[kk][cq * 4] = *(const float4*)&W[(size_t)(kb + kk) * 40 + cq * 4];
        }
        __syncthreads();
#pragma unroll
        for (int k = 0; k < BK; ++k) {
            float4 xv = *(const float4*)&Xs[k][ng * 4];
            float4 wv = *(const float4*)&Ws[k][cg * 4];
            float xa[4] = {xv.x, xv.y, xv.z, xv.w};
            float wa[4] = {wv.x, wv.y, wv.z, wv.w};
#pragma unroll
            for (int j = 0; j < 4; ++j)
#pragma unroll
                for (int c = 0; c < 4; ++c)
                    acc[j][c] = fmaf(xa[j], wa[c], acc[j][c]);
        }
        __syncthreads();
    }

    float4 bv = *(const float4*)&bias[cg * 4];
#pragma unroll
    for (int j = 0; j < 4; ++j) {
        int gnode = node0 + ng * 4 + j;
        if (gnode < n) {
            float4 o = make_float4(acc[j][0] + bv.x, acc[j][1] + bv.y,
                                   acc[j][2] + bv.z, acc[j][3] + bv.w);
            *(float4*)&out[(size_t)gnode * 40 + cg * 4] = o;
        }
    }
}

// ---------------- host ------------------------------------------------------
extern "C" void kernel_launch(void* const* d_in, const int* in_sizes, int n_in,
                              void* d_out, int out_size, void* d_ws, size_t ws_size,
                              hipStream_t stream)
{
    const float* x        = (const float*)d_in[0];
    const int*   eidx     = (const int*)d_in[1];
    const float* gat_W1   = (const float*)d_in[2];
    const float* att_s1   = (const float*)d_in[3];
    const float* att_d1   = (const float*)d_in[4];
    const float* gat_b1   = (const float*)d_in[5];
    const float* gat_W2   = (const float*)d_in[6];
    const float* att_s2   = (const float*)d_in[7];
    const float* att_d2   = (const float*)d_in[8];
    const float* gat_b2   = (const float*)d_in[9];
    const float* gcn_W1   = (const float*)d_in[10];
    const float* gcn_b1   = (const float*)d_in[11];
    const float* gcn_W2   = (const float*)d_in[12];
    const float* gcn_b2   = (const float*)d_in[13];
    const float* lin_W    = (const float*)d_in[14];
    const float* lin_b    = (const float*)d_in[15];
    const float* wc_p     = (const float*)d_in[16];
    const float* wt_p     = (const float*)d_in[17];

    const int n = in_sizes[0] / F_IN;      // 50000
    const int e = in_sizes[1] / 2;         // 800000
    const int* src = eidx;
    const int* dst = eidx + e;
    const int NBUCK = (n + 127) >> 7;      // 391

    char* p = (char*)d_ws;
    auto alloc = [&](size_t bytes) -> void* {
        void* r = (void*)p;
        p += (bytes + 255) & ~(size_t)255;
        return r;
    };
    unsigned* rs      = (unsigned*)alloc((size_t)(n + 1) * 4);
    unsigned* cursor  = (unsigned*)alloc((size_t)n * 4);
    unsigned* bcnt    = (unsigned*)alloc((size_t)(NBUCK + 1) * 4);
    unsigned* bprefix = (unsigned*)alloc((size_t)NBUCK * 4);
    unsigned* csr_src = (unsigned*)alloc((size_t)e * 4);
    uint4*    wbf     = (uint4*)alloc(40 * 64 * 16);
    float* nrm     = (float*)alloc((size_t)n * 4);
    float* as1     = (float*)alloc((size_t)n * 4 * 4);
    float* ad1     = (float*)alloc((size_t)n * 4 * 4);
    float* as2     = (float*)alloc((size_t)n * 4);
    float* ad2     = (float*)alloc((size_t)n * 4);
    unsigned* regA = (unsigned*)alloc((size_t)n * 80 * 4); // bpair/ovf -> h1g -> catb
    unsigned* hg_b = (unsigned*)alloc((size_t)n * 40 * 4);
    unsigned* xgb  = (unsigned*)alloc((size_t)n * 64 * 4);
    unsigned* gaccb= (unsigned*)alloc((size_t)n * 16 * 4);
    // aliases with disjoint lifetimes (stream-ordered):
    unsigned* bpair = regA;
    uint2*    ovf   = (uint2*)(bpair + (size_t)NBUCK * BCAP);
    unsigned* h1g   = regA;     // [n,80u] after CSR build; dead after agg1
    unsigned* catb  = regA;     // [n,40u] written by agg2 (after agg1)
    unsigned* ovf_cnt = bcnt + NBUCK;

    const int WB = (n + 3) / 4;
    const int SB = (e + SCHUNK - 1) / SCHUNK;

    // ---- CSR build (5 dispatches; bpair read once) ----
    hipMemsetAsync(bcnt, 0, (size_t)(NBUCK + 1) * 4, stream);
    bucket_scatter_kernel<<<SB, 256, 0, stream>>>(src, dst, bcnt, bpair, ovf_cnt, ovf, e, NBUCK);
    bucket_prefix_kernel<<<1, 512, 0, stream>>>(bcnt, bprefix, rs, NBUCK, n, (unsigned)e);
    bucket_build_kernel<<<NBUCK, 256, 0, stream>>>(bcnt, bpair, bprefix, ovf_cnt, ovf,
                                                   rs, nrm, csr_src, cursor, n);
    overflow_fill_kernel<<<1, 256, 0, stream>>>(ovf_cnt, ovf, cursor, csr_src);

    // ---- W pre-pack + MFMA first-layer GEMM (combined h1g + logits1) ----
    wb_prep_kernel<<<40, 64, 0, stream>>>(gat_W1, gcn_W1, wbf);
    gemm1_mfma_kernel<<<(n + 63) / 64, 256, 0, stream>>>(x, wbf, att_s1, att_d1,
                                                         h1g, as1, ad1, n);

    // ---- fused layer-1 aggregation (one combined-row walk) ----
    agg1_fused_kernel<<<WB, 256, 0, stream>>>(h1g, as1, ad1, nrm, rs, csr_src,
                                              gat_b1, gcn_b1, xgb, gaccb, n);

    // ---- merged layer-2 GEMMs (+logits2) -> hg_b ----
    gemm2_fused_kernel<<<(n + 127) / 128, 320, 0, stream>>>(xgb, gaccb, gat_W2, gcn_W2,
                                                            att_s2, att_d2, hg_b, as2, ad2, n);

    // ---- fused layer-2 aggregation -> catb (bf16) ----
    agg2_fused_kernel<<<WB, 256, 0, stream>>>(hg_b, as2, ad2, nrm, rs, csr_src,
                                              gat_b2, gcn_b2, wc_p, wt_p, catb, n);

    // ---- head ----
    gemm_head_kernel<<<(n + 127) / 128, 320, 0, stream>>>(catb, lin_W, lin_b, (float*)d_out, n);
}